// Round 8
// baseline (293.039 us; speedup 1.0000x reference)
//
#include <hip/hip_runtime.h>
#include <stdint.h>

#define MDIM 4096
#define NDIM 4096
#define KDIM 4096

#define BM 128
#define BN 128
#define BK 64
#define NT (KDIM / BK)

typedef __attribute__((ext_vector_type(8))) __bf16 bf16x8;
typedef __attribute__((ext_vector_type(4))) float f32x4;
typedef __attribute__((ext_vector_type(8))) unsigned short ushort8_t;
typedef __attribute__((ext_vector_type(4))) unsigned short ushort4_t;

typedef const __attribute__((address_space(1))) void* gas_ptr;
typedef __attribute__((address_space(3))) void* las_ptr;

__device__ __forceinline__ void async_load16(const void* g, void* l) {
    // global -> LDS direct DMA, 16B/lane; LDS dest = wave-uniform base + lane*16
    __builtin_amdgcn_global_load_lds((gas_ptr)g, (las_ptr)l, 16, 0, 0);
}

__device__ __forceinline__ unsigned short f32_to_bf16_rne(float f) {
    union { float f; uint32_t u; } v; v.f = f;
    uint32_t u = v.u;
    return (unsigned short)((u + 0x7FFFu + ((u >> 16) & 1u)) >> 16);
}

__device__ __forceinline__ unsigned short sgn_bf16(float w) {
    return (w > 0.f) ? 0x3F80u : ((w < 0.f) ? 0xBF80u : 0u);
}

// ---------------- fused prep kernel (R2-verified, unchanged) ----------------

#define XBLKS 2048

__global__ void prep_kernel(const float* __restrict__ x, const float* __restrict__ W,
                            unsigned short* __restrict__ xbf, unsigned short* __restrict__ wqT) {
    if (blockIdx.x < XBLKS) {
        const int tot8 = MDIM * KDIM / 8;
        int t = blockIdx.x * 256 + threadIdx.x;
        const int stride = XBLKS * 256;
        for (int i = t; i < tot8; i += stride) {
            float4 v0 = ((const float4*)x)[2 * i];
            float4 v1 = ((const float4*)x)[2 * i + 1];
            ushort8_t o;
            o[0] = f32_to_bf16_rne(v0.x); o[1] = f32_to_bf16_rne(v0.y);
            o[2] = f32_to_bf16_rne(v0.z); o[3] = f32_to_bf16_rne(v0.w);
            o[4] = f32_to_bf16_rne(v1.x); o[5] = f32_to_bf16_rne(v1.y);
            o[6] = f32_to_bf16_rne(v1.z); o[7] = f32_to_bf16_rne(v1.w);
            ((ushort8_t*)xbf)[i] = o;
        }
    } else {
        __shared__ __align__(16) unsigned short tile[64][68];
        const int wb = blockIdx.x - XBLKS;
        const int n0 = (wb & 63) * 64;
        const int k0 = (wb >> 6) * 64;
        const int t  = threadIdx.x;
#pragma unroll
        for (int r = 0; r < 2; ++r) {
            int flat = r * 256 + t;
            int k2   = flat >> 4;
            int nch  = (flat & 15) * 4;
            const float* s0 = &W[(size_t)(k0 + 2 * k2) * NDIM + n0 + nch];
            float4 v0 = *(const float4*)(s0);
            float4 v1 = *(const float4*)(s0 + NDIM);
            const float* f0 = (const float*)&v0;
            const float* f1 = (const float*)&v1;
#pragma unroll
            for (int j = 0; j < 4; ++j) {
                union { unsigned short u[2]; unsigned int w; } p;
                p.u[0] = sgn_bf16(f0[j]);
                p.u[1] = sgn_bf16(f1[j]);
                *(unsigned int*)&tile[nch + j][2 * k2] = p.w;
            }
        }
        __syncthreads();
#pragma unroll
        for (int r = 0; r < 2; ++r) {
            int flat = r * 256 + t;
            int n    = flat >> 3;
            int kch  = (flat & 7) * 8;
            ushort4_t a = *(const ushort4_t*)&tile[n][kch];
            ushort4_t b = *(const ushort4_t*)&tile[n][kch + 4];
            ushort8_t o;
            o[0] = a[0]; o[1] = a[1]; o[2] = a[2]; o[3] = a[3];
            o[4] = b[0]; o[5] = b[1]; o[6] = b[2]; o[7] = b[3];
            *(ushort8_t*)&wqT[(size_t)(n0 + n) * KDIM + k0 + kch] = o;
        }
    }
}

// ---- GEMM R8: 128x128 tile, 4 waves, 2 BLOCKS PER CU (two barrier domains) ----
// R2 schedule verbatim (both-sides XOR swizzle, lockstep phases, coarse last-phase
// staging, boundary vmcnt(8)); geometry shrunk so LDS = 64KB -> 2 blocks/CU.
// Mechanism (m114): one block's barrier/lgkm serialization hides under the other
// block's MFMA. Grid 32x32 = 1024 = exactly 2 co-residency rounds, zero tail.
// Per wave: output 64x64 (acc[4][4]); per tile: 16 ds_read_b128, 32 MFMA,
// 8 staged DMAs (identical vmcnt accounting to R2).

__global__ __launch_bounds__(256, 2) void gemm_bf16_bt(
        const unsigned short* __restrict__ A,
        const unsigned short* __restrict__ Bt,
        const float* __restrict__ bias,
        float* __restrict__ C)
{
    __shared__ __align__(16) unsigned short lds[2][2][BM * BK];  // 64 KB

    const int tid  = threadIdx.x;
    const int wave = tid >> 6;          // 0..3
    const int lane = tid & 63;
    const int wm = wave >> 1;           // 0..1 -> 64-row slice
    const int wn = wave & 1;            // 0..1 -> 64-col slice

    // XCD swizzle: grid 32x32 = 1024, 128 tiles per XCD as an 8(m) x 16(n) rect
    int o   = blockIdx.y * gridDim.x + blockIdx.x;   // 0..1023
    int xcd = o & 7, ii = o >> 3;                    // ii: 0..127
    int bmi = (xcd >> 1) * 8 + (ii >> 4);            // 0..31
    int bni = (xcd & 1) * 16 + (ii & 15);            // 0..31
    const int bm = bmi * BM;
    const int bn = bni * BN;

    // staging: group g (8 rows x 128B = 1KB) -> LDS linear; lane l: row = l>>3,
    // source chunk = (l&7) ^ row  (pre-swizzled source, linear dest)
    const int lrow = lane >> 3;
    const int lchk = (lane & 7) ^ lrow;
    const size_t aSrc = (size_t)(bm + lrow) * KDIM + lchk * 8;
    const size_t bSrc = (size_t)(bn + lrow) * KDIM + lchk * 8;
    const int g0 = wave * 4;            // 4 waves x 4 groups = 16 groups = 16KB

#define STAGE_A(BUF, TK, G) async_load16(A  + aSrc + (size_t)(G) * (8 * KDIM) + (TK), \
                                         &lds[BUF][0][(G) * 512])
#define STAGE_B(BUF, TK, G) async_load16(Bt + bSrc + (size_t)(G) * (8 * KDIM) + (TK), \
                                         &lds[BUF][1][(G) * 512])

    // fragment reads (XOR-swizzled), identical row geometry to R2 (128B rows)
    const int frow = lane & 15;
    const int rb  = frow * 128;
    const int cx0 = ((lane >> 4) ^ (lane & 7)) << 4;
    const int cx1 = cx0 ^ 64;

    const char* L = (const char*)lds;
    // per buf: A @ 0, B @ 16384; buf1 at +32768
    const char* aP00 = L +     0 + wm * 8192 + rb + cx0;
    const char* aP01 = L +     0 + wm * 8192 + rb + cx1;
    const char* aP10 = L + 32768 + wm * 8192 + rb + cx0;
    const char* aP11 = L + 32768 + wm * 8192 + rb + cx1;
    const char* bP00 = L + 16384 + wn * 8192 + rb + cx0;
    const char* bP01 = L + 16384 + wn * 8192 + rb + cx1;
    const char* bP10 = L + 49152 + wn * 8192 + rb + cx0;
    const char* bP11 = L + 49152 + wn * 8192 + rb + cx1;

    f32x4 acc[4][4] = {};
    bf16x8 af[4][2];
    bf16x8 bfr[4][2];

#define MFMA8(NI)                                                               \
    _Pragma("unroll")                                                           \
    for (int mi = 0; mi < 4; ++mi)                                              \
        _Pragma("unroll")                                                       \
        for (int ks = 0; ks < 2; ++ks)                                          \
            acc[mi][NI] = __builtin_amdgcn_mfma_f32_16x16x32_bf16(              \
                af[mi][ks], bfr[NI][ks], acc[mi][NI], 0, 0, 0);

#define STAGE_TILE(BUF, TK)                                      \
    do {                                                         \
        STAGE_A(BUF, TK, g0 + 0); STAGE_A(BUF, TK, g0 + 1);      \
        STAGE_A(BUF, TK, g0 + 2); STAGE_A(BUF, TK, g0 + 3);      \
        STAGE_B(BUF, TK, g0 + 0); STAGE_B(BUF, TK, g0 + 1);      \
        STAGE_B(BUF, TK, g0 + 2); STAGE_B(BUF, TK, g0 + 3);      \
    } while (0)

    // prologue: tile0 -> buf0, tile1 -> buf1; wait only tile0's 8 loads
    STAGE_TILE(0, 0);
    STAGE_TILE(1, BK);
    asm volatile("s_waitcnt vmcnt(8)" ::: "memory");
    __builtin_amdgcn_s_barrier();
    asm volatile("" ::: "memory");
    __builtin_amdgcn_sched_barrier(0);

    for (int t = 0; t < NT; ++t) {
        const bool odd  = t & 1;
        const char* aK0 = odd ? aP10 : aP00;
        const char* aK1 = odd ? aP11 : aP01;
        const char* bK0 = odd ? bP10 : bP00;
        const char* bK1 = odd ? bP11 : bP01;
        const int  cur  = odd ? 1 : 0;

        // ---- phase 0: read af (8) + bfr[0,1] (4); MFMA n0,n1 (16) ----
#pragma unroll
        for (int mi = 0; mi < 4; ++mi) {
            af[mi][0] = *(const bf16x8*)(aK0 + mi * 2048);
            af[mi][1] = *(const bf16x8*)(aK1 + mi * 2048);
        }
#pragma unroll
        for (int ni = 0; ni < 2; ++ni) {
            bfr[ni][0] = *(const bf16x8*)(bK0 + ni * 2048);
            bfr[ni][1] = *(const bf16x8*)(bK1 + ni * 2048);
        }
        __builtin_amdgcn_s_barrier();
        __builtin_amdgcn_s_setprio(1);
        MFMA8(0)
        MFMA8(1)
        __builtin_amdgcn_s_setprio(0);
        __builtin_amdgcn_s_barrier();

        // ---- phase 1: read bfr[2,3] (4); MFMA n2 (8) ----
#pragma unroll
        for (int ni = 2; ni < 4; ++ni) {
            bfr[ni][0] = *(const bf16x8*)(bK0 + ni * 2048);
            bfr[ni][1] = *(const bf16x8*)(bK1 + ni * 2048);
        }
        __builtin_amdgcn_s_barrier();
        __builtin_amdgcn_s_setprio(1);
        MFMA8(2)
        __builtin_amdgcn_s_setprio(0);
        __builtin_amdgcn_s_barrier();
        // all reads of buf[cur] retired globally -> safe to overwrite

        // ---- phase 2: stage tile t+2 -> buf[cur]; MFMA n3 (8) ----
        if (t + 2 < NT) {
            STAGE_TILE(cur, (t + 2) * BK);
        }
        __builtin_amdgcn_s_setprio(1);
        MFMA8(3)
        __builtin_amdgcn_s_setprio(0);

        // boundary: retire tile t+1's 8 loads; keep t+2's 8 in flight
        if (t + 2 < NT) {
            asm volatile("s_waitcnt vmcnt(8)" ::: "memory");
        } else if (t + 1 < NT) {
            asm volatile("s_waitcnt vmcnt(0)" ::: "memory");
        }
        if (t + 1 < NT) {
            __builtin_amdgcn_s_barrier();
            asm volatile("" ::: "memory");
            __builtin_amdgcn_sched_barrier(0);
        }
    }

    // ---- epilogue (direct stores): col=lane&15, row=(lane>>4)*4+reg ----
#pragma unroll
    for (int ni = 0; ni < 4; ++ni) {
        int col = bn + wn * 64 + ni * 16 + frow;
        float bv = bias[col];
#pragma unroll
        for (int mi = 0; mi < 4; ++mi) {
            int row0 = bm + wm * 64 + mi * 16 + (lane >> 4) * 4;
#pragma unroll
            for (int r = 0; r < 4; ++r)
                C[(size_t)(row0 + r) * NDIM + col] = acc[mi][ni][r] + bv;
        }
    }
#undef STAGE_A
#undef STAGE_B
#undef STAGE_TILE
#undef MFMA8
}

// ---------------- fallback ----------------

__global__ void fallback_gemm(const float* __restrict__ x, const float* __restrict__ W,
                              const float* __restrict__ b, float* __restrict__ out) {
    __shared__ float As[32][32];
    __shared__ float Bs[32][33];
    int tx = threadIdx.x, ty = threadIdx.y;
    int row = blockIdx.y * 32 + ty;
    int col = blockIdx.x * 32 + tx;
    float acc = 0.0f;
    for (int kt = 0; kt < KDIM; kt += 32) {
        As[ty][tx] = x[(size_t)row * KDIM + kt + tx];
        float w = W[(size_t)(kt + ty) * NDIM + col];
        Bs[ty][tx] = (w > 0.0f) ? 1.0f : ((w < 0.0f) ? -1.0f : 0.0f);
        __syncthreads();
#pragma unroll
        for (int k = 0; k < 32; ++k) acc += As[ty][k] * Bs[k][tx];
        __syncthreads();
    }
    out[(size_t)row * NDIM + col] = acc + b[col];
}

extern "C" void kernel_launch(void* const* d_in, const int* in_sizes, int n_in,
                              void* d_out, int out_size, void* d_ws, size_t ws_size,
                              hipStream_t stream) {
    const float* x = (const float*)d_in[0];
    const float* W = (const float*)d_in[1];
    const float* b = (const float*)d_in[2];
    float* out = (float*)d_out;

    const size_t need = (size_t)MDIM * KDIM * 2 + (size_t)KDIM * NDIM * 2;
    if (ws_size >= need) {
        unsigned short* xbf = (unsigned short*)d_ws;
        unsigned short* wqT = xbf + (size_t)MDIM * KDIM;
        prep_kernel<<<XBLKS + (NDIM / 64) * (KDIM / 64), 256, 0, stream>>>(x, W, xbf, wqT);
        gemm_bf16_bt<<<dim3(NDIM / BN, MDIM / BM), 256, 0, stream>>>(xbf, wqT, b, out);
    } else {
        fallback_gemm<<<dim3(NDIM / 32, MDIM / 32), dim3(32, 32), 0, stream>>>(x, W, b, out);
    }
}

// Round 10
// 279.817 us; speedup vs baseline: 1.0473x; 1.0473x over previous
//
#include <hip/hip_runtime.h>
#include <stdint.h>

#define MDIM 4096
#define NDIM 4096
#define KDIM 4096

#define BM 256
#define BN 256
#define BK 64
#define NT (KDIM / BK)

typedef __attribute__((ext_vector_type(8))) __bf16 bf16x8;
typedef __attribute__((ext_vector_type(4))) float f32x4;
typedef __attribute__((ext_vector_type(8))) unsigned short ushort8_t;
typedef __attribute__((ext_vector_type(4))) unsigned short ushort4_t;

typedef const __attribute__((address_space(1))) void* gas_ptr;
typedef __attribute__((address_space(3))) void* las_ptr;

__device__ __forceinline__ void async_load16(const void* g, void* l) {
    // global -> LDS direct DMA, 16B/lane; LDS dest = wave-uniform base + lane*16
    __builtin_amdgcn_global_load_lds((gas_ptr)g, (las_ptr)l, 16, 0, 0);
}

__device__ __forceinline__ unsigned short f32_to_bf16_rne(float f) {
    union { float f; uint32_t u; } v; v.f = f;
    uint32_t u = v.u;
    return (unsigned short)((u + 0x7FFFu + ((u >> 16) & 1u)) >> 16);
}

__device__ __forceinline__ unsigned short sgn_bf16(float w) {
    return (w > 0.f) ? 0x3F80u : ((w < 0.f) ? 0xBF80u : 0u);
}

// ---------------- fused prep kernel (R2-verified, unchanged) ----------------

#define XBLKS 2048

__global__ void prep_kernel(const float* __restrict__ x, const float* __restrict__ W,
                            unsigned short* __restrict__ xbf, unsigned short* __restrict__ wqT) {
    if (blockIdx.x < XBLKS) {
        const int tot8 = MDIM * KDIM / 8;
        int t = blockIdx.x * 256 + threadIdx.x;
        const int stride = XBLKS * 256;
        for (int i = t; i < tot8; i += stride) {
            float4 v0 = ((const float4*)x)[2 * i];
            float4 v1 = ((const float4*)x)[2 * i + 1];
            ushort8_t o;
            o[0] = f32_to_bf16_rne(v0.x); o[1] = f32_to_bf16_rne(v0.y);
            o[2] = f32_to_bf16_rne(v0.z); o[3] = f32_to_bf16_rne(v0.w);
            o[4] = f32_to_bf16_rne(v1.x); o[5] = f32_to_bf16_rne(v1.y);
            o[6] = f32_to_bf16_rne(v1.z); o[7] = f32_to_bf16_rne(v1.w);
            ((ushort8_t*)xbf)[i] = o;
        }
    } else {
        __shared__ __align__(16) unsigned short tile[64][68];
        const int wb = blockIdx.x - XBLKS;
        const int n0 = (wb & 63) * 64;
        const int k0 = (wb >> 6) * 64;
        const int t  = threadIdx.x;
#pragma unroll
        for (int r = 0; r < 2; ++r) {
            int flat = r * 256 + t;
            int k2   = flat >> 4;
            int nch  = (flat & 15) * 4;
            const float* s0 = &W[(size_t)(k0 + 2 * k2) * NDIM + n0 + nch];
            float4 v0 = *(const float4*)(s0);
            float4 v1 = *(const float4*)(s0 + NDIM);
            const float* f0 = (const float*)&v0;
            const float* f1 = (const float*)&v1;
#pragma unroll
            for (int j = 0; j < 4; ++j) {
                union { unsigned short u[2]; unsigned int w; } p;
                p.u[0] = sgn_bf16(f0[j]);
                p.u[1] = sgn_bf16(f1[j]);
                *(unsigned int*)&tile[nch + j][2 * k2] = p.w;
            }
        }
        __syncthreads();
#pragma unroll
        for (int r = 0; r < 2; ++r) {
            int flat = r * 256 + t;
            int n    = flat >> 3;
            int kch  = (flat & 7) * 8;
            ushort4_t a = *(const ushort4_t*)&tile[n][kch];
            ushort4_t b = *(const ushort4_t*)&tile[n][kch + 4];
            ushort8_t o;
            o[0] = a[0]; o[1] = a[1]; o[2] = a[2]; o[3] = a[3];
            o[4] = b[0]; o[5] = b[1]; o[6] = b[2]; o[7] = b[3];
            *(ushort8_t*)&wqT[(size_t)(n0 + n) * KDIM + k0 + kch] = o;
        }
    }
}

// ---- GEMM R9: R2 pipeline + FAITHFUL per-phase uniform half-tile staging ----
// 256x256 tile, 8 waves, 16x16x32 MFMA, both-sides XOR swizzle.
// Read/MFMA/barrier skeleton = R2 verbatim (12/4/8/0 reads; 16 MFMA; barrier
// pairs; setprio). Staging = m201-style: EVERY phase, ALL waves issue 2 DMAs of
// one uniform half-tile whose LDS region went read-free >= 1 barrier earlier:
//   ph0 -> (t+1).A-m1  (region last read (t-1).ph2)   into buf[nxt]
//   ph1 -> (t+1).B-n0  (last read (t-1).ph0)          into buf[nxt]
//   ph2 -> (t+2).A-m0  (last read this tile ph0)      into buf[cur]
//   ph3 -> (t+2).B-n1  (last read this tile ph1)      into buf[cur]
// Boundary: 12 outstanding; vmcnt(4) retires the oldest 8 = ALL of tile t+1's
// loads; keeps tile t+2's 4 in flight. vmcnt(0) only at t=NT-2.
// Half-tile group sets (groups = 8-row/1KB units; per wave 2 groups each):
//   A-m0: {w, w+16}   A-m1: {w+8, w+24}
//   B-n0: {bq, bq+1}  B-n1: {bq+4, bq+5},  bq = (w>>1)*8 + (w&1)*2

__global__ __launch_bounds__(512, 2) void gemm_bf16_bt(
        const unsigned short* __restrict__ A,
        const unsigned short* __restrict__ Bt,
        const float* __restrict__ bias,
        float* __restrict__ C)
{
    __shared__ __align__(16) unsigned short lds[2][2][BM * BK];

    const int tid  = threadIdx.x;
    const int wave = tid >> 6;
    const int lane = tid & 63;
    const int wm = wave >> 2;
    const int wn = wave & 3;

    int o   = blockIdx.y * gridDim.x + blockIdx.x;
    int xcd = o & 7, ii = o >> 3;
    int bmi = (xcd >> 1) * 4 + (ii >> 3);
    int bni = (xcd & 1) * 8 + (ii & 7);
    const int bm = bmi * BM;
    const int bn = bni * BN;

    const int lrow = lane >> 3;
    const int lchk = (lane & 7) ^ lrow;
    const size_t aSrc = (size_t)(bm + lrow) * KDIM + lchk * 8;
    const size_t bSrc = (size_t)(bn + lrow) * KDIM + lchk * 8;

    // half-tile staging groups (uniform across phases, 2 per wave per phase)
    const int aM0_0 = wave,      aM0_1 = wave + 16;
    const int aM1_0 = wave + 8,  aM1_1 = wave + 24;
    const int bq    = ((wave >> 1) << 3) + ((wave & 1) << 1);
    const int bN0_0 = bq,        bN0_1 = bq + 1;
    const int bN1_0 = bq + 4,    bN1_1 = bq + 5;

#define SA(BUF, TK, G) async_load16(A  + aSrc + (size_t)(G) * (8 * KDIM) + (TK), \
                                    &lds[BUF][0][(G) * 512])
#define SB(BUF, TK, G) async_load16(Bt + bSrc + (size_t)(G) * (8 * KDIM) + (TK), \
                                    &lds[BUF][1][(G) * 512])

    const int frow = lane & 15;
    const int rb  = frow * 128;
    const int cx0 = ((lane >> 4) ^ (lane & 7)) << 4;
    const int cx1 = cx0 ^ 64;

    const char* L = (const char*)lds;
    const char* aP00 = L +     0 + wm * 16384 + rb + cx0;
    const char* aP01 = L +     0 + wm * 16384 + rb + cx1;
    const char* aP10 = L + 65536 + wm * 16384 + rb + cx0;
    const char* aP11 = L + 65536 + wm * 16384 + rb + cx1;
    const char* bP00 = L + 32768 +         wn * 8192 + rb + cx0;
    const char* bP01 = L + 32768 +         wn * 8192 + rb + cx1;
    const char* bP10 = L + 98304 +         wn * 8192 + rb + cx0;
    const char* bP11 = L + 98304 +         wn * 8192 + rb + cx1;

    f32x4 acc[8][4] = {};
    bf16x8 af[4][2];
    bf16x8 bfr[4][2];

#define MFMA16(MIB, NIB)                                                        \
    _Pragma("unroll")                                                           \
    for (int mi = 0; mi < 4; ++mi)                                              \
        _Pragma("unroll")                                                       \
        for (int ni = 0; ni < 2; ++ni)                                          \
            _Pragma("unroll")                                                   \
            for (int ks = 0; ks < 2; ++ks)                                      \
                acc[(MIB) + mi][(NIB) + ni] =                                   \
                    __builtin_amdgcn_mfma_f32_16x16x32_bf16(                    \
                        af[mi][ks], bfr[(NIB) + ni][ks],                        \
                        acc[(MIB) + mi][(NIB) + ni], 0, 0, 0);

    // ---- prologue: tile0 fully (8), tile1 {A-m0, B-n1} (4); retire tile0 ----
    SA(0, 0, aM0_0); SA(0, 0, aM0_1);
    SA(0, 0, aM1_0); SA(0, 0, aM1_1);
    SB(0, 0, bN0_0); SB(0, 0, bN0_1);
    SB(0, 0, bN1_0); SB(0, 0, bN1_1);
    SA(1, BK, aM0_0); SA(1, BK, aM0_1);
    SB(1, BK, bN1_0); SB(1, BK, bN1_1);
    asm volatile("s_waitcnt vmcnt(4)" ::: "memory");
    __builtin_amdgcn_s_barrier();
    asm volatile("" ::: "memory");
    __builtin_amdgcn_sched_barrier(0);

    for (int t = 0; t < NT; ++t) {
        const bool odd  = t & 1;
        const char* aK0 = odd ? aP10 : aP00;
        const char* aK1 = odd ? aP11 : aP01;
        const char* bK0 = odd ? bP10 : bP00;
        const char* bK1 = odd ? bP11 : bP01;
        const int  cur  = odd ? 1 : 0;
        const int  nxt  = cur ^ 1;
        const int  tk1  = (t + 1) * BK;
        const int  tk2  = (t + 2) * BK;

        // ---- phase 0: read af(grp0)+bfr(n0,n1); stage (t+1).A-m1 ----
#pragma unroll
        for (int mi = 0; mi < 4; ++mi) {
            af[mi][0] = *(const bf16x8*)(aK0 + mi * 2048);
            af[mi][1] = *(const bf16x8*)(aK1 + mi * 2048);
        }
#pragma unroll
        for (int ni = 0; ni < 2; ++ni) {
            bfr[ni][0] = *(const bf16x8*)(bK0 + ni * 2048);
            bfr[ni][1] = *(const bf16x8*)(bK1 + ni * 2048);
        }
        if (t + 1 < NT) { SA(nxt, tk1, aM1_0); SA(nxt, tk1, aM1_1); }
        __builtin_amdgcn_s_barrier();
        __builtin_amdgcn_s_setprio(1);
        MFMA16(0, 0)
        __builtin_amdgcn_s_setprio(0);
        __builtin_amdgcn_s_barrier();

        // ---- phase 1: read bfr(n2,n3); stage (t+1).B-n0 ----
#pragma unroll
        for (int ni = 2; ni < 4; ++ni) {
            bfr[ni][0] = *(const bf16x8*)(bK0 + ni * 2048);
            bfr[ni][1] = *(const bf16x8*)(bK1 + ni * 2048);
        }
        if (t + 1 < NT) { SB(nxt, tk1, bN0_0); SB(nxt, tk1, bN0_1); }
        __builtin_amdgcn_s_barrier();
        __builtin_amdgcn_s_setprio(1);
        MFMA16(0, 2)
        __builtin_amdgcn_s_setprio(0);
        __builtin_amdgcn_s_barrier();

        // ---- phase 2: read af(grp1); stage (t+2).A-m0 ----
#pragma unroll
        for (int mi = 0; mi < 4; ++mi) {
            af[mi][0] = *(const bf16x8*)(aK0 + 8192 + mi * 2048);
            af[mi][1] = *(const bf16x8*)(aK1 + 8192 + mi * 2048);
        }
        if (t + 2 < NT) { SA(cur, tk2, aM0_0); SA(cur, tk2, aM0_1); }
        __builtin_amdgcn_s_barrier();
        __builtin_amdgcn_s_setprio(1);
        MFMA16(4, 2)
        __builtin_amdgcn_s_setprio(0);
        __builtin_amdgcn_s_barrier();

        // ---- phase 3: stage (t+2).B-n1; pure MFMA ----
        if (t + 2 < NT) { SB(cur, tk2, bN1_0); SB(cur, tk2, bN1_1); }
        __builtin_amdgcn_s_setprio(1);
        MFMA16(4, 0)
        __builtin_amdgcn_s_setprio(0);

        // ---- boundary: retire ALL of tile t+1's loads (oldest 8 of 12);
        //      keep tile t+2's 4 in flight ----
        if (t + 2 < NT) {
            asm volatile("s_waitcnt vmcnt(4)" ::: "memory");
        } else if (t + 1 < NT) {
            asm volatile("s_waitcnt vmcnt(0)" ::: "memory");
        }
        if (t + 1 < NT) {
            __builtin_amdgcn_s_barrier();
            asm volatile("" ::: "memory");
            __builtin_amdgcn_sched_barrier(0);
        }
    }

    // ---- epilogue (R2 direct stores): col=lane&15, row=(lane>>4)*4+reg ----
#pragma unroll
    for (int ni = 0; ni < 4; ++ni) {
        int col = bn + wn * 64 + ni * 16 + frow;
        float bv = bias[col];
#pragma unroll
        for (int mig = 0; mig < 8; ++mig) {
            int row0 = bm + wm * 128 + mig * 16 + (lane >> 4) * 4;
#pragma unroll
            for (int r = 0; r < 4; ++r)
                C[(size_t)(row0 + r) * NDIM + col] = acc[mig][ni][r] + bv;
        }
    }
#undef SA
#undef SB
#undef MFMA16
}

// ---------------- fallback ----------------

__global__ void fallback_gemm(const float* __restrict__ x, const float* __restrict__ W,
                              const float* __restrict__ b, float* __restrict__ out) {
    __shared__ float As[32][32];
    __shared__ float Bs[32][33];
    int tx = threadIdx.x, ty = threadIdx.y;
    int row = blockIdx.y * 32 + ty;
    int col = blockIdx.x * 32 + tx;
    float acc = 0.0f;
    for (int kt = 0; kt < KDIM; kt += 32) {
        As[ty][tx] = x[(size_t)row * KDIM + kt + tx];
        float w = W[(size_t)(kt + ty) * NDIM + col];
        Bs[ty][tx] = (w > 0.0f) ? 1.0f : ((w < 0.0f) ? -1.0f : 0.0f);
        __syncthreads();
#pragma unroll
        for (int k = 0; k < 32; ++k) acc += As[ty][k] * Bs[k][tx];
        __syncthreads();
    }
    out[(size_t)row * NDIM + col] = acc + b[col];
}

extern "C" void kernel_launch(void* const* d_in, const int* in_sizes, int n_in,
                              void* d_out, int out_size, void* d_ws, size_t ws_size,
                              hipStream_t stream) {
    const float* x = (const float*)d_in[0];
    const float* W = (const float*)d_in[1];
    const float* b = (const float*)d_in[2];
    float* out = (float*)d_out;

    const size_t need = (size_t)MDIM * KDIM * 2 + (size_t)KDIM * NDIM * 2;
    if (ws_size >= need) {
        unsigned short* xbf = (unsigned short*)d_ws;
        unsigned short* wqT = xbf + (size_t)MDIM * KDIM;
        prep_kernel<<<XBLKS + (NDIM / 64) * (KDIM / 64), 256, 0, stream>>>(x, W, xbf, wqT);
        gemm_bf16_bt<<<dim3(NDIM / BN, MDIM / BM), 512, 0, stream>>>(xbf, wqT, b, out);
    } else {
        fallback_gemm<<<dim3(NDIM / 32, MDIM / 32), dim3(32, 32), 0, stream>>>(x, W, b, out);
    }
}